// Round 19
// baseline (92.907 us; speedup 1.0000x reference)
//
#include <hip/hip_runtime.h>
#include <hip/hip_fp16.h>

// LGA2 fused: out = LGA(LGA(x,f),f), radius=2 (25 taps), fp32 in/out.
// x: [N=2, C=64, H=256, W=512], f: [N, 25, H, W], out like x.
//
// R19 = R18's pk_fma compute + R15's (correctness-proven) single-barrier
// pipelined sync + 2-deep prefetch, with the spill fixed:
//  - amdgpu_waves_per_eu(3,3): VGPR budget ~170 (need ~86) -> prefetch regs
//    and packed filters stay resident (R15 spilled at the default ceiling).
//    3 blocks/CU cap == grid's 3.09/CU.
//  - ONE lgkm barrier per channel: st double-buffered; audit: every LDS
//    buffer's write->read separated by >=1 barrier, read->rewrite by >=1.
//  - 2-deep prefetch: x(c+2) issued at iter c, landed iter c+1 (~1.2 iters
//    in flight >> ~900cy HBM latency). Loop x2-unrolled for static parity.
// Compute verbatim R17/R18: v_pk_fma_f16, two f16 chains merged by pk_add,
// f16 LDS, CPB=32. Tile: temp 16x64, out 12x60, x 20x68, USH=40.

typedef __fp16 h2v __attribute__((ext_vector_type(2)));

#define OH 12
#define OW 60
#define USH 40

__device__ __forceinline__ unsigned pkh(float a, float b) {
    union { h2v h; unsigned u; } c;
    c.h = __builtin_amdgcn_cvt_pkrtz(a, b);
    return c.u;
}

// packed: ac.h[i] += fv.h[i] * xv.h[i]
#define PKF(ac, fv, xv) \
    asm("v_pk_fma_f16 %0, %1, %2, %0" : "+v"(ac) : "v"(fv), "v"(xv));

// filter row i (taps 5i..5i+4) vs window uints w0..w3 (rel halves 0..7).
#define ROWP(i, w0, w1, w2, w3, D01, D23) { \
    const unsigned A01 = ((w0) >> 16) | ((w1) << 16); \
    const unsigned A12 = ((w1) >> 16) | ((w2) << 16); \
    const unsigned A23 = ((w2) >> 16) | ((w3) << 16); \
    PKF(D01, frA[5*(i)+0], w0)  PKF(D01, frA[5*(i)+1], A01) \
    PKF(D01, frA[5*(i)+2], w1)  PKF(D01, frA[5*(i)+3], A12) \
    PKF(D01, frA[5*(i)+4], w2) \
    PKF(D23, frB[5*(i)+0], w1)  PKF(D23, frB[5*(i)+1], A12) \
    PKF(D23, frB[5*(i)+2], w2)  PKF(D23, frB[5*(i)+3], A23) \
    PKF(D23, frB[5*(i)+4], w3) }

// One pass over 5 rows starting at ROWBASE in BUF; results s01,s23 packed f16.
#define PASSP(BUF, ROWBASE) { \
    unsigned e01 = 0u, o01 = 0u, e23 = 0u, o23 = 0u; \
    _Pragma("unroll") \
    for (int i = 0; i < 5; ++i) { \
        const int b = ((ROWBASE) + i) * USH + 2 * s; \
        uint2 lo = *(const uint2*)&(BUF)[b]; \
        uint2 hi = *(const uint2*)&(BUF)[b + 2]; \
        if (i & 1) { ROWP(i, lo.x, lo.y, hi.x, hi.y, o01, o23) } \
        else       { ROWP(i, lo.x, lo.y, hi.x, hi.y, e01, e23) } \
    } \
    asm("v_pk_add_f16 %0, %1, %2" : "=v"(s01) : "v"(e01), "v"(o01)); \
    asm("v_pk_add_f16 %0, %1, %2" : "=v"(s23) : "v"(e23), "v"(o23)); }

// lgkm-only barrier: LDS ordered, global prefetch loads stay in flight
#define LBAR() { asm volatile("s_waitcnt lgkmcnt(0)" ::: "memory"); \
                 __builtin_amdgcn_s_barrier(); asm volatile("" ::: "memory"); }

// Channel CC: issue x(CC+2)->NXI; p1 from SXR -> STB; land NXL(=x(CC+1))
// -> SXL; BAR; p2 from STB -> out.
#define BODY(CC, SXR, SXL, STB, NXI0, NXI1, NXL0, NXL1) { \
    if ((CC) + 2 < CPB) { \
        if (ok0) NXI0 = *(const float4*)pfp0; \
        if (ok1) NXI1 = *(const float4*)pfp1; \
    } \
    pfp0 += HW; pfp1 += HW; \
    unsigned s01, s23; \
    PASSP(SXR, r) \
    (STB)[r * USH + 1 + 2 * s] = s01; \
    (STB)[r * USH + 2 + 2 * s] = s23; \
    if ((CC) + 1 < CPB) { \
        *(uint2*)&(SXL)[l0u] = make_uint2(pkh(NXL0.x, NXL0.y), pkh(NXL0.z, NXL0.w)); \
        if (has1) *(uint2*)&(SXL)[l1u] = make_uint2(pkh(NXL1.x, NXL1.y), pkh(NXL1.z, NXL1.w)); \
    } \
    LBAR(); \
    PASSP(STB, rc - 2) \
    if (prow) { \
        union { unsigned u; h2v h; } U01, U23; \
        U01.u = s01; U23.u = s23; \
        if (s >= 1 && gwb + 1 < W) \
            *(float2*)op = make_float2((float)U01.h.x, (float)U01.h.y); \
        if (s <= 14 && gwb + 3 < W) \
            *(float2*)(op + 2) = make_float2((float)U23.h.x, (float)U23.h.y); \
    } \
    op += HW; \
}

__global__ __launch_bounds__(256)
__attribute__((amdgpu_waves_per_eu(3, 3)))
void lga2_fused(const float* __restrict__ x, const float* __restrict__ f,
                float* __restrict__ out, int N, int C, int H, int W, int CPB) {
    const int tid = threadIdx.x;
    const int r = tid >> 4;            // temp-region row 0..15
    const int s = tid & 15;            // quad-strip 0..15
    const int oh0 = blockIdx.y * OH;
    const int ow0 = blockIdx.x * OW;
    const int CG = C / CPB;
    const int n  = blockIdx.z / CG;
    const int c0 = (blockIdx.z % CG) * CPB;
    const int HW = H * W;

    __shared__ unsigned sx0[20 * USH], sx1[20 * USH];  // x as f16, dbuf
    __shared__ unsigned st0[16 * USH], st1[16 * USH];  // temp as f16, dbuf

    // zero temp guard uints (uint 0 = halves 0,1; uint 33 = halves 66,67)
    if (tid < 64) {
        unsigned* stz = (tid < 32) ? st0 : st1;
        int i = tid & 31, row = i & 15;
        stz[row * USH + ((i & 16) ? 33 : 0)] = 0u;
    }

    // ---- filter registers: 25 taps x 2 packed half2 ----
    const int gh_f = oh0 - 2 + r;
    const int gwb  = ow0 - 2 + 4 * s;
    const bool rowok = (gh_f >= 0) && (gh_f < H);
    const bool p0ok = rowok && (gwb >= 0) && (gwb + 1 < W);
    const bool p1ok = rowok && (gwb + 3 < W);
    const float* fb = f + (size_t)(n * 25) * HW + (size_t)(rowok ? gh_f : 0) * W;

    unsigned frA[25], frB[25];
    #pragma unroll
    for (int t = 0; t < 25; ++t) {
        float2 v01 = p0ok ? *(const float2*)(fb + (size_t)t * HW + gwb)
                          : make_float2(0.f, 0.f);
        float2 v23 = p1ok ? *(const float2*)(fb + (size_t)t * HW + gwb + 2)
                          : make_float2(0.f, 0.f);
        frA[t] = pkh(v01.x, v01.y);
        frB[t] = pkh(v23.x, v23.y);
        if (t == 12) __builtin_amdgcn_sched_barrier(0);  // 2 load batches
    }
    #pragma unroll
    for (int t = 0; t < 25; ++t)
        asm volatile("" : "+v"(frA[t]), "+v"(frB[t]));   // pin packed filters

    // ---- staging: 340 quads (20 rows x 17), linear uint2 per quad ----
    const int i1 = tid + 256;
    const bool has1 = (tid < 340 - 256);
    const int row0 = tid / 17, v0 = tid - row0 * 17;
    const int row1 = i1 / 17,  v1 = i1 - row1 * 17;
    const int g0h = oh0 - 4 + row0, g0c = ow0 - 4 + 4 * v0;
    const int g1h = oh0 - 4 + row1, g1c = ow0 - 4 + 4 * v1;
    const bool ok0 = (g0h >= 0) && (g0h < H) && (g0c >= 0) && (g0c + 3 < W);
    const bool ok1 = has1 && (g1h >= 0) && (g1h < H) && (g1c >= 0) && (g1c + 3 < W);
    const int off0 = ok0 ? (g0h * W + g0c) : 0;
    const int off1 = ok1 ? (g1h * W + g1c) : 0;
    const int l0u = row0 * USH + 2 * v0;
    const int l1u = row1 * USH + 2 * v1;

    const float4 z4 = make_float4(0.f, 0.f, 0.f, 0.f);
    const float* xc = x + (size_t)(n * C + c0) * HW;

    // prologue: stage ch0 -> sx0; issue ch1 -> nxB regs; pointers at ch2
    {
        float4 p = ok0 ? *(const float4*)(xc + off0) : z4;
        *(uint2*)&sx0[l0u] = make_uint2(pkh(p.x, p.y), pkh(p.z, p.w));
        if (has1) {
            float4 q = ok1 ? *(const float4*)(xc + off1) : z4;
            *(uint2*)&sx0[l1u] = make_uint2(pkh(q.x, q.y), pkh(q.z, q.w));
        }
    }
    float4 nxA0 = z4, nxA1 = z4, nxB0 = z4, nxB1 = z4;
    if (CPB > 1) {
        if (ok0) nxB0 = *(const float4*)(xc + HW + off0);
        if (ok1) nxB1 = *(const float4*)(xc + HW + off1);
    }
    const float* pfp0 = xc + 2 * (size_t)HW + off0;
    const float* pfp1 = xc + 2 * (size_t)HW + off1;
    __syncthreads();

    const bool prow = (r >= 2) && (r <= 13) && (gh_f < H);
    const int rc = (r < 2) ? 2 : ((r > 13) ? 13 : r);
    float* op = out + ((size_t)(n * C + c0) * H + gh_f) * W + gwb;

    for (int cc = 0; cc < CPB; cc += 2) {
        BODY(cc,     sx0, sx1, st0, nxA0, nxA1, nxB0, nxB1)   // even channel
        BODY(cc + 1, sx1, sx0, st1, nxB0, nxB1, nxA0, nxA1)   // odd channel
    }
}

extern "C" void kernel_launch(void* const* d_in, const int* in_sizes, int n_in,
                              void* d_out, int out_size, void* d_ws, size_t ws_size,
                              hipStream_t stream) {
    const float* x = (const float*)d_in[0];
    const float* f = (const float*)d_in[1];
    float* out = (float*)d_out;

    const int N = 2, C = 64, H = 256, W = 512;
    const int CPB = 32;                        // 2 channel groups
    const int CG = C / CPB;

    dim3 grid((W + OW - 1) / OW,               // 9
              (H + OH - 1) / OH,               // 22
              N * CG);                         // 4  -> 792 blocks of 256 thr
    lga2_fused<<<grid, 256, 0, stream>>>(x, f, out, N, C, H, W, CPB);
}

// Round 20
// 71.825 us; speedup vs baseline: 1.2935x; 1.2935x over previous
//
#include <hip/hip_runtime.h>
#include <hip/hip_fp16.h>

// LGA2 fused: out = LGA(LGA(x,f),f), radius=2 (25 taps), fp32 in/out.
// x: [N=2, C=64, H=256, W=512], f: [N, 25, H, W], out like x.
//
// R20 = R18 compute + channel-pair ILP:
//  - 2 channels per iteration: {issue pf(c+2,c+3); p1(c)->stA; p1(c+1)->stB;
//    BAR; p2(stA); p2(stB); land pf->next bufs; BAR}. Two independent
//    dependency chains per phase (2x latency overlap), 1 barrier/channel
//    (was 2), prefetch window = full iteration.
//  - 4 rotating x-buffers (sxA..sxD); stA/stB single-buffered (write->read
//    and read->rewrite each cross a barrier - audited safe).
//  - NO waves_per_eu (R19 lesson). CPB=32, pk_fma compute verbatim R18.
// Tile: temp 16x64, out 12x60, x 20x68, USH=40 uints/row (f16 LDS).

typedef __fp16 h2v __attribute__((ext_vector_type(2)));

#define OH 12
#define OW 60
#define USH 40

__device__ __forceinline__ unsigned pkh(float a, float b) {
    union { h2v h; unsigned u; } c;
    c.h = __builtin_amdgcn_cvt_pkrtz(a, b);
    return c.u;
}

// packed: ac.h[i] += fv.h[i] * xv.h[i]
#define PKF(ac, fv, xv) \
    asm("v_pk_fma_f16 %0, %1, %2, %0" : "+v"(ac) : "v"(fv), "v"(xv));

// filter row i (taps 5i..5i+4) vs window uints w0..w3 (rel halves 0..7).
#define ROWP(i, w0, w1, w2, w3, D01, D23) { \
    const unsigned A01 = ((w0) >> 16) | ((w1) << 16); \
    const unsigned A12 = ((w1) >> 16) | ((w2) << 16); \
    const unsigned A23 = ((w2) >> 16) | ((w3) << 16); \
    PKF(D01, frA[5*(i)+0], w0)  PKF(D01, frA[5*(i)+1], A01) \
    PKF(D01, frA[5*(i)+2], w1)  PKF(D01, frA[5*(i)+3], A12) \
    PKF(D01, frA[5*(i)+4], w2) \
    PKF(D23, frB[5*(i)+0], w1)  PKF(D23, frB[5*(i)+1], A12) \
    PKF(D23, frB[5*(i)+2], w2)  PKF(D23, frB[5*(i)+3], A23) \
    PKF(D23, frB[5*(i)+4], w3) }

// One pass over 5 rows from ROWBASE in BUF; outputs packed f16 S01,S23.
#define PASSP(BUF, ROWBASE, S01, S23) { \
    unsigned e01 = 0u, o01 = 0u, e23 = 0u, o23 = 0u; \
    _Pragma("unroll") \
    for (int i = 0; i < 5; ++i) { \
        const int b = ((ROWBASE) + i) * USH + 2 * s; \
        uint2 lo = *(const uint2*)&(BUF)[b]; \
        uint2 hi = *(const uint2*)&(BUF)[b + 2]; \
        if (i & 1) { ROWP(i, lo.x, lo.y, hi.x, hi.y, o01, o23) } \
        else       { ROWP(i, lo.x, lo.y, hi.x, hi.y, e01, e23) } \
    } \
    asm("v_pk_add_f16 %0, %1, %2" : "=v"(S01) : "v"(e01), "v"(o01)); \
    asm("v_pk_add_f16 %0, %1, %2" : "=v"(S23) : "v"(e23), "v"(o23)); }

// lgkm-only barrier: LDS ordered, global prefetch loads stay in flight
#define LBAR() { asm volatile("s_waitcnt lgkmcnt(0)" ::: "memory"); \
                 __builtin_amdgcn_s_barrier(); asm volatile("" ::: "memory"); }

// store packed pair to global (f32)
#define STOREOUT(P, S01, S23) { \
    union { unsigned u; h2v h; } U01, U23; \
    U01.u = S01; U23.u = S23; \
    if (s >= 1 && gwb + 1 < W) \
        *(float2*)(P) = make_float2((float)U01.h.x, (float)U01.h.y); \
    if (s <= 14 && gwb + 3 < W) \
        *(float2*)((P) + 2) = make_float2((float)U23.h.x, (float)U23.h.y); }

// Two channels CC, CC+1: read SXa/SXb, land prefetch into SXc/SXd.
#define BODY2(CC, SXa, SXb, SXc, SXd) { \
    float4 n0p = z4, n0q = z4, n1p = z4, n1q = z4; \
    if ((CC) + 2 < CPB) { \
        if (ok0) n0p = *(const float4*)pfp0; \
        if (ok1) n0q = *(const float4*)pfp1; \
    } \
    if ((CC) + 3 < CPB) { \
        if (ok0) n1p = *(const float4*)(pfp0 + HW); \
        if (ok1) n1q = *(const float4*)(pfp1 + HW); \
    } \
    pfp0 += 2 * (size_t)HW; pfp1 += 2 * (size_t)HW; \
    unsigned sa01, sa23, sb01, sb23; \
    PASSP(SXa, r, sa01, sa23) \
    PASSP(SXb, r, sb01, sb23) \
    stA[r * USH + 1 + 2 * s] = sa01; \
    stA[r * USH + 2 + 2 * s] = sa23; \
    stB[r * USH + 1 + 2 * s] = sb01; \
    stB[r * USH + 2 + 2 * s] = sb23; \
    LBAR(); \
    PASSP(stA, rc - 2, sa01, sa23) \
    PASSP(stB, rc - 2, sb01, sb23) \
    if (prow) { \
        STOREOUT(op, sa01, sa23) \
        STOREOUT(op + HW, sb01, sb23) \
    } \
    if ((CC) + 2 < CPB) { \
        *(uint2*)&(SXc)[l0u] = make_uint2(pkh(n0p.x, n0p.y), pkh(n0p.z, n0p.w)); \
        if (has1) *(uint2*)&(SXc)[l1u] = make_uint2(pkh(n0q.x, n0q.y), pkh(n0q.z, n0q.w)); \
    } \
    if ((CC) + 3 < CPB) { \
        *(uint2*)&(SXd)[l0u] = make_uint2(pkh(n1p.x, n1p.y), pkh(n1p.z, n1p.w)); \
        if (has1) *(uint2*)&(SXd)[l1u] = make_uint2(pkh(n1q.x, n1q.y), pkh(n1q.z, n1q.w)); \
    } \
    LBAR(); \
    op += 2 * (size_t)HW; \
}

__global__ __launch_bounds__(256)
void lga2_fused(const float* __restrict__ x, const float* __restrict__ f,
                float* __restrict__ out, int N, int C, int H, int W, int CPB) {
    const int tid = threadIdx.x;
    const int r = tid >> 4;            // temp-region row 0..15
    const int s = tid & 15;            // quad-strip 0..15
    const int oh0 = blockIdx.y * OH;
    const int ow0 = blockIdx.x * OW;
    const int CG = C / CPB;
    const int n  = blockIdx.z / CG;
    const int c0 = (blockIdx.z % CG) * CPB;
    const int HW = H * W;

    __shared__ unsigned sxA[20 * USH], sxB[20 * USH];
    __shared__ unsigned sxC[20 * USH], sxD[20 * USH];
    __shared__ unsigned stA[16 * USH], stB[16 * USH];

    // zero temp guard uints (uint 0 = halves 0,1; uint 33 = halves 66,67)
    if (tid < 64) {
        unsigned* stz = (tid < 32) ? stA : stB;
        int i = tid & 31, row = i & 15;
        stz[row * USH + ((i & 16) ? 33 : 0)] = 0u;
    }

    // ---- filter registers: 25 taps x 2 packed half2 ----
    const int gh_f = oh0 - 2 + r;
    const int gwb  = ow0 - 2 + 4 * s;
    const bool rowok = (gh_f >= 0) && (gh_f < H);
    const bool p0ok = rowok && (gwb >= 0) && (gwb + 1 < W);
    const bool p1ok = rowok && (gwb + 3 < W);
    const float* fb = f + (size_t)(n * 25) * HW + (size_t)(rowok ? gh_f : 0) * W;

    unsigned frA[25], frB[25];
    #pragma unroll
    for (int t = 0; t < 25; ++t) {
        float2 v01 = p0ok ? *(const float2*)(fb + (size_t)t * HW + gwb)
                          : make_float2(0.f, 0.f);
        float2 v23 = p1ok ? *(const float2*)(fb + (size_t)t * HW + gwb + 2)
                          : make_float2(0.f, 0.f);
        frA[t] = pkh(v01.x, v01.y);
        frB[t] = pkh(v23.x, v23.y);
        if (t == 12) __builtin_amdgcn_sched_barrier(0);  // 2 load batches
    }
    #pragma unroll
    for (int t = 0; t < 25; ++t)
        asm volatile("" : "+v"(frA[t]), "+v"(frB[t]));   // pin packed filters

    // ---- staging: 340 quads (20 rows x 17), linear uint2 per quad ----
    const int i1 = tid + 256;
    const bool has1 = (tid < 340 - 256);
    const int row0 = tid / 17, v0 = tid - row0 * 17;
    const int row1 = i1 / 17,  v1 = i1 - row1 * 17;
    const int g0h = oh0 - 4 + row0, g0c = ow0 - 4 + 4 * v0;
    const int g1h = oh0 - 4 + row1, g1c = ow0 - 4 + 4 * v1;
    const bool ok0 = (g0h >= 0) && (g0h < H) && (g0c >= 0) && (g0c + 3 < W);
    const bool ok1 = has1 && (g1h >= 0) && (g1h < H) && (g1c >= 0) && (g1c + 3 < W);
    const int off0 = ok0 ? (g0h * W + g0c) : 0;
    const int off1 = ok1 ? (g1h * W + g1c) : 0;
    const int l0u = row0 * USH + 2 * v0;
    const int l1u = row1 * USH + 2 * v1;

    const float4 z4 = make_float4(0.f, 0.f, 0.f, 0.f);
    const float* xc = x + (size_t)(n * C + c0) * HW;

    {   // prologue: stage ch0 -> sxA, ch1 -> sxB
        float4 p = ok0 ? *(const float4*)(xc + off0) : z4;
        *(uint2*)&sxA[l0u] = make_uint2(pkh(p.x, p.y), pkh(p.z, p.w));
        float4 q = ok0 ? *(const float4*)(xc + HW + off0) : z4;
        *(uint2*)&sxB[l0u] = make_uint2(pkh(q.x, q.y), pkh(q.z, q.w));
        if (has1) {
            float4 p1v = ok1 ? *(const float4*)(xc + off1) : z4;
            *(uint2*)&sxA[l1u] = make_uint2(pkh(p1v.x, p1v.y), pkh(p1v.z, p1v.w));
            float4 q1v = ok1 ? *(const float4*)(xc + HW + off1) : z4;
            *(uint2*)&sxB[l1u] = make_uint2(pkh(q1v.x, q1v.y), pkh(q1v.z, q1v.w));
        }
    }
    __syncthreads();

    const bool prow = (r >= 2) && (r <= 13) && (gh_f < H);
    const int rc = (r < 2) ? 2 : ((r > 13) ? 13 : r);
    float* op = out + ((size_t)(n * C + c0) * H + gh_f) * W + gwb;
    const float* pfp0 = xc + 2 * (size_t)HW + off0;
    const float* pfp1 = xc + 2 * (size_t)HW + off1;

    for (int cc = 0; cc < CPB; cc += 4) {
        BODY2(cc,     sxA, sxB, sxC, sxD)
        BODY2(cc + 2, sxC, sxD, sxA, sxB)
    }
}

extern "C" void kernel_launch(void* const* d_in, const int* in_sizes, int n_in,
                              void* d_out, int out_size, void* d_ws, size_t ws_size,
                              hipStream_t stream) {
    const float* x = (const float*)d_in[0];
    const float* f = (const float*)d_in[1];
    float* out = (float*)d_out;

    const int N = 2, C = 64, H = 256, W = 512;
    const int CPB = 32;                        // 2 channel groups
    const int CG = C / CPB;

    dim3 grid((W + OW - 1) / OW,               // 9
              (H + OH - 1) / OH,               // 22
              N * CG);                         // 4  -> 792 blocks of 256 thr
    lga2_fused<<<grid, 256, 0, stream>>>(x, f, out, N, C, H, W, CPB);
}

// Round 21
// 69.671 us; speedup vs baseline: 1.3335x; 1.0309x over previous
//
#include <hip/hip_runtime.h>
#include <hip/hip_fp16.h>

// LGA2 fused: out = LGA(LGA(x,f),f), radius=2 (25 taps), fp32 in/out.
// x: [N=2, C=64, H=256, W=512], f: [N, 25, H, W], out like x.
//
// R21: channel-pair packing. The two f16 halves of every LDS/compute word
// hold the SAME pixel for channels (c, c+1), not adjacent pixels.
//  - x operand of (tap j, col k) = one LDS uint -> ZERO alignbit repacks
//    (was 15/pass); filter halves broadcast via VOP3P op_sel (no extra regs).
//  - One LDS buffer serves 2 channels: 10 ds_read_b128/pass per pair
//    (was 20 b64); staging/temp bytes unchanged.
//  - frA[t]=(f@col0,f@col1), frB[t]=(f@col2,f@col3): 50 regs, as proven.
//  - Sync: per pair {issue pf(next pair); p1; BAR; p2+stores; land pf; BAR}
//    = 1 barrier/channel (R20 rate). st single-buffered (audited).
// Tile: temp 16x64, out 12x60, x 20x68. USH=76 uints/row (pixel-packed).

typedef __fp16 h2v __attribute__((ext_vector_type(2)));

#define OH 12
#define OW 60
#define USH 76

__device__ __forceinline__ unsigned pkh(float a, float b) {
    union { h2v h; unsigned u; } c;
    c.h = __builtin_amdgcn_cvt_pkrtz(a, b);
    return c.u;
}

// acc.h[ch] += fv.LO * xv.h[ch]  (filter lo-half broadcast to both channels)
#define PKFL(ac, fv, xv) \
    asm("v_pk_fma_f16 %0, %1, %2, %0 op_sel:[0,0,0] op_sel_hi:[0,1,1]" \
        : "+v"(ac) : "v"(fv), "v"(xv));
// acc.h[ch] += fv.HI * xv.h[ch]  (filter hi-half broadcast)
#define PKFH(ac, fv, xv) \
    asm("v_pk_fma_f16 %0, %1, %2, %0 op_sel:[1,0,0] op_sel_hi:[1,1,1]" \
        : "+v"(ac) : "v"(fv), "v"(xv));

// filter row (taps T..T+4) vs 8 window uints qa.x..qb.w (pixel 4s..4s+7,
// channel-pair packed). Col k tap j reads uint (k+j). Accs A0..A3 per col.
#define ROW8(T, qa, qb, A0, A1, A2, A3) \
  PKFL(A0, frA[T+0], qa.x) PKFH(A1, frA[T+0], qa.y) PKFL(A2, frB[T+0], qa.z) PKFH(A3, frB[T+0], qa.w) \
  PKFL(A0, frA[T+1], qa.y) PKFH(A1, frA[T+1], qa.z) PKFL(A2, frB[T+1], qa.w) PKFH(A3, frB[T+1], qb.x) \
  PKFL(A0, frA[T+2], qa.z) PKFH(A1, frA[T+2], qa.w) PKFL(A2, frB[T+2], qb.x) PKFH(A3, frB[T+2], qb.y) \
  PKFL(A0, frA[T+3], qa.w) PKFH(A1, frA[T+3], qb.x) PKFL(A2, frB[T+3], qb.y) PKFH(A3, frB[T+3], qb.z) \
  PKFL(A0, frA[T+4], qb.x) PKFH(A1, frA[T+4], qb.y) PKFL(A2, frB[T+4], qb.z) PKFH(A3, frB[T+4], qb.w)

// One pass (5 rows from ROWBASE) over channel-pair-packed BUF; outputs 4
// packed col results S0..S3 (each = (ch_c, ch_c1) f16).
#define PASS2(BUF, ROWBASE, S0, S1, S2, S3) { \
    unsigned e0=0u,e1=0u,e2=0u,e3=0u,o0=0u,o1=0u,o2=0u,o3=0u; \
    _Pragma("unroll") \
    for (int i = 0; i < 5; ++i) { \
        const int b = ((ROWBASE) + i) * USH + 4 * s; \
        uint4 qa = *(const uint4*)&(BUF)[b]; \
        uint4 qb = *(const uint4*)&(BUF)[b + 4]; \
        if (i & 1) { ROW8(5*i, qa, qb, o0, o1, o2, o3) } \
        else       { ROW8(5*i, qa, qb, e0, e1, e2, e3) } \
    } \
    asm("v_pk_add_f16 %0, %1, %2" : "=v"(S0) : "v"(e0), "v"(o0)); \
    asm("v_pk_add_f16 %0, %1, %2" : "=v"(S1) : "v"(e1), "v"(o1)); \
    asm("v_pk_add_f16 %0, %1, %2" : "=v"(S2) : "v"(e2), "v"(o2)); \
    asm("v_pk_add_f16 %0, %1, %2" : "=v"(S3) : "v"(e3), "v"(o3)); }

// lgkm-only barrier: LDS ordered, global prefetch loads stay in flight
#define LBAR() { asm volatile("s_waitcnt lgkmcnt(0)" ::: "memory"); \
                 __builtin_amdgcn_s_barrier(); asm volatile("" ::: "memory"); }

__global__ __launch_bounds__(256)
void lga2_fused(const float* __restrict__ x, const float* __restrict__ f,
                float* __restrict__ out, int N, int C, int H, int W, int CPB) {
    const int tid = threadIdx.x;
    const int r = tid >> 4;            // temp-region row 0..15
    const int s = tid & 15;            // quad-strip 0..15
    const int oh0 = blockIdx.y * OH;
    const int ow0 = blockIdx.x * OW;
    const int CG = C / CPB;
    const int n  = blockIdx.z / CG;
    const int c0 = (blockIdx.z % CG) * CPB;
    const int HW = H * W;

    __shared__ unsigned sxU[2][20 * USH];   // x, channel-pair packed f16
    __shared__ unsigned stU[16 * USH];      // temp, channel-pair packed f16

    // zero temp guard uints 0,1,66,67 per row
    if (tid < 64) {
        int row = tid >> 2, q = tid & 3;
        stU[row * USH + (q < 2 ? q : q + 64)] = 0u;
    }

    // ---- filter registers: 25 taps x 2 packed (col pairs), proven layout ----
    const int gh_f = oh0 - 2 + r;
    const int gwb  = ow0 - 2 + 4 * s;
    const bool rowok = (gh_f >= 0) && (gh_f < H);
    const bool p0ok = rowok && (gwb >= 0) && (gwb + 1 < W);
    const bool p1ok = rowok && (gwb + 3 < W);
    const float* fb = f + (size_t)(n * 25) * HW + (size_t)(rowok ? gh_f : 0) * W;

    unsigned frA[25], frB[25];
    #pragma unroll
    for (int t = 0; t < 25; ++t) {
        float2 v01 = p0ok ? *(const float2*)(fb + (size_t)t * HW + gwb)
                          : make_float2(0.f, 0.f);
        float2 v23 = p1ok ? *(const float2*)(fb + (size_t)t * HW + gwb + 2)
                          : make_float2(0.f, 0.f);
        frA[t] = pkh(v01.x, v01.y);
        frB[t] = pkh(v23.x, v23.y);
        if (t == 12) __builtin_amdgcn_sched_barrier(0);  // 2 load batches
    }
    #pragma unroll
    for (int t = 0; t < 25; ++t)
        asm volatile("" : "+v"(frA[t]), "+v"(frB[t]));   // pin packed filters

    // ---- staging: 340 quads (20 rows x 17 x 4 pixels), b128 per quad ----
    const int i1 = tid + 256;
    const bool has1 = (tid < 340 - 256);
    const int row0 = tid / 17, v0 = tid - row0 * 17;
    const int row1 = i1 / 17,  v1 = i1 - row1 * 17;
    const int g0h = oh0 - 4 + row0, g0c = ow0 - 4 + 4 * v0;
    const int g1h = oh0 - 4 + row1, g1c = ow0 - 4 + 4 * v1;
    const bool ok0 = (g0h >= 0) && (g0h < H) && (g0c >= 0) && (g0c + 3 < W);
    const bool ok1 = has1 && (g1h >= 0) && (g1h < H) && (g1c >= 0) && (g1c + 3 < W);
    const int off0 = ok0 ? (g0h * W + g0c) : 0;
    const int off1 = ok1 ? (g1h * W + g1c) : 0;
    const int l0u = row0 * USH + 4 * v0;   // b128-aligned
    const int l1u = row1 * USH + 4 * v1;

    const float4 z4 = make_float4(0.f, 0.f, 0.f, 0.f);
    const float* xc = x + (size_t)(n * C + c0) * HW;

#define PACK4(pa, pb) make_uint4(pkh(pa.x, pb.x), pkh(pa.y, pb.y), \
                                 pkh(pa.z, pb.z), pkh(pa.w, pb.w))

    {   // prologue: stage channel pair (0,1) -> buffer 0
        float4 pa = ok0 ? *(const float4*)(xc + off0) : z4;
        float4 pb = ok0 ? *(const float4*)(xc + HW + off0) : z4;
        *(uint4*)&sxU[0][l0u] = PACK4(pa, pb);
        if (has1) {
            float4 qa = ok1 ? *(const float4*)(xc + off1) : z4;
            float4 qb = ok1 ? *(const float4*)(xc + HW + off1) : z4;
            *(uint4*)&sxU[0][l1u] = PACK4(qa, qb);
        }
    }
    __syncthreads();

    const bool prow = (r >= 2) && (r <= 13) && (gh_f < H);
    const int rc = (r < 2) ? 2 : ((r > 13) ? 13 : r);
    float* op = out + ((size_t)(n * C + c0) * H + gh_f) * W + gwb;

    int cur = 0;
    for (int cp = 0; cp < CPB; cp += 2) {
        // issue prefetch for pair (cp+2, cp+3); landed at iteration end
        float4 n0a = z4, n0b = z4, n1a = z4, n1b = z4;
        const bool pf = (cp + 2 < CPB);
        if (pf) {
            const float* xn = xc + (size_t)(cp + 2) * HW;
            if (ok0) { n0a = *(const float4*)(xn + off0);
                       n0b = *(const float4*)(xn + HW + off0); }
            if (ok1) { n1a = *(const float4*)(xn + off1);
                       n1b = *(const float4*)(xn + HW + off1); }
        }

        // ---- pass 1: temp(r, cols 4s..4s+3) for both channels ----
        unsigned t0, t1, t2, t3;
        PASS2(sxU[cur], r, t0, t1, t2, t3)
        *(uint2*)&stU[r * USH + 2 + 4 * s] = make_uint2(t0, t1);
        *(uint2*)&stU[r * USH + 4 + 4 * s] = make_uint2(t2, t3);
        LBAR();   // temp visible

        // ---- pass 2 + stores ----
        PASS2(stU, rc - 2, t0, t1, t2, t3)
        if (prow) {
            union { unsigned u; h2v h; } U0, U1, U2, U3;
            U0.u = t0; U1.u = t1; U2.u = t2; U3.u = t3;
            float* oq = op + HW;   // channel cp+1
            if (s >= 1 && gwb + 1 < W) {
                *(float2*)op = make_float2((float)U0.h.x, (float)U1.h.x);
                *(float2*)oq = make_float2((float)U0.h.y, (float)U1.h.y);
            }
            if (s <= 14 && gwb + 3 < W) {
                *(float2*)(op + 2) = make_float2((float)U2.h.x, (float)U3.h.x);
                *(float2*)(oq + 2) = make_float2((float)U2.h.y, (float)U3.h.y);
            }
        }

        // ---- land prefetch into the other buffer ----
        if (pf) {
            unsigned* d = sxU[cur ^ 1];
            *(uint4*)&d[l0u] = PACK4(n0a, n0b);
            if (has1) *(uint4*)&d[l1u] = PACK4(n1a, n1b);
        }
        LBAR();   // next pair's x visible; temp reads drained
        cur ^= 1;
        op += 2 * (size_t)HW;
    }
}

extern "C" void kernel_launch(void* const* d_in, const int* in_sizes, int n_in,
                              void* d_out, int out_size, void* d_ws, size_t ws_size,
                              hipStream_t stream) {
    const float* x = (const float*)d_in[0];
    const float* f = (const float*)d_in[1];
    float* out = (float*)d_out;

    const int N = 2, C = 64, H = 256, W = 512;
    const int CPB = 32;                        // 2 channel groups
    const int CG = C / CPB;

    dim3 grid((W + OW - 1) / OW,               // 9
              (H + OH - 1) / OH,               // 22
              N * CG);                         // 4  -> 792 blocks of 256 thr
    lga2_fused<<<grid, 256, 0, stream>>>(x, f, out, N, C, H, W, CPB);
}

// Round 22
// 69.465 us; speedup vs baseline: 1.3375x; 1.0030x over previous
//
#include <hip/hip_runtime.h>
#include <hip/hip_fp16.h>

// LGA2 fused: out = LGA(LGA(x,f),f), radius=2 (25 taps), fp32 in/out.
// x: [N=2, C=64, H=256, W=512], f: [N, 25, H, W], out like x.
//
// R22 = R21 (69.7us, passed) with ONE change: LDS inflated 17.4->29.2KB
// (x-buffer array [2]->[4], slices 2/3 dummy-used) to bind max occupancy at
// 5 blocks/CU. Mechanism: the RA's VGPR target = 512/(max waves/SIMD from
// LDS+blocksize); at <=18KB that is 8 -> 64-VGPR clamp -> the 50 pinned
// filter regs + working set spilled to scratch EVERY round R13-R21
// (VGPR_Count 56-64 < need ~80). At 29.2KB the budget is ~102 -> no spill.
// Grid provides only 3.1 blocks/CU, so the 5-block cap costs nothing.
//
// R21 structure: channel-pair packing (two f16 halves = same pixel, chans
// c/c+1), zero repacks via VOP3P op_sel filter broadcast, 10 ds_read_b128
// per pass per pair, 1 lgkm-only barrier per channel, 1-iter-deep prefetch.
// Tile: temp 16x64, out 12x60, x 20x68. USH=76 uints/row.

typedef __fp16 h2v __attribute__((ext_vector_type(2)));

#define OH 12
#define OW 60
#define USH 76

__device__ __forceinline__ unsigned pkh(float a, float b) {
    union { h2v h; unsigned u; } c;
    c.h = __builtin_amdgcn_cvt_pkrtz(a, b);
    return c.u;
}

// acc.h[ch] += fv.LO * xv.h[ch]  (filter lo-half broadcast to both channels)
#define PKFL(ac, fv, xv) \
    asm("v_pk_fma_f16 %0, %1, %2, %0 op_sel:[0,0,0] op_sel_hi:[0,1,1]" \
        : "+v"(ac) : "v"(fv), "v"(xv));
// acc.h[ch] += fv.HI * xv.h[ch]  (filter hi-half broadcast)
#define PKFH(ac, fv, xv) \
    asm("v_pk_fma_f16 %0, %1, %2, %0 op_sel:[1,0,0] op_sel_hi:[1,1,1]" \
        : "+v"(ac) : "v"(fv), "v"(xv));

// filter row (taps T..T+4) vs 8 window uints qa.x..qb.w (pixel 4s..4s+7,
// channel-pair packed). Col k tap j reads uint (k+j). Accs A0..A3 per col.
#define ROW8(T, qa, qb, A0, A1, A2, A3) \
  PKFL(A0, frA[T+0], qa.x) PKFH(A1, frA[T+0], qa.y) PKFL(A2, frB[T+0], qa.z) PKFH(A3, frB[T+0], qa.w) \
  PKFL(A0, frA[T+1], qa.y) PKFH(A1, frA[T+1], qa.z) PKFL(A2, frB[T+1], qa.w) PKFH(A3, frB[T+1], qb.x) \
  PKFL(A0, frA[T+2], qa.z) PKFH(A1, frA[T+2], qa.w) PKFL(A2, frB[T+2], qb.x) PKFH(A3, frB[T+2], qb.y) \
  PKFL(A0, frA[T+3], qa.w) PKFH(A1, frA[T+3], qb.x) PKFL(A2, frB[T+3], qb.y) PKFH(A3, frB[T+3], qb.z) \
  PKFL(A0, frA[T+4], qb.x) PKFH(A1, frA[T+4], qb.y) PKFL(A2, frB[T+4], qb.z) PKFH(A3, frB[T+4], qb.w)

// One pass (5 rows from ROWBASE) over channel-pair-packed BUF; outputs 4
// packed col results S0..S3 (each = (ch_c, ch_c1) f16).
#define PASS2(BUF, ROWBASE, S0, S1, S2, S3) { \
    unsigned e0=0u,e1=0u,e2=0u,e3=0u,o0=0u,o1=0u,o2=0u,o3=0u; \
    _Pragma("unroll") \
    for (int i = 0; i < 5; ++i) { \
        const int b = ((ROWBASE) + i) * USH + 4 * s; \
        uint4 qa = *(const uint4*)&(BUF)[b]; \
        uint4 qb = *(const uint4*)&(BUF)[b + 4]; \
        if (i & 1) { ROW8(5*i, qa, qb, o0, o1, o2, o3) } \
        else       { ROW8(5*i, qa, qb, e0, e1, e2, e3) } \
    } \
    asm("v_pk_add_f16 %0, %1, %2" : "=v"(S0) : "v"(e0), "v"(o0)); \
    asm("v_pk_add_f16 %0, %1, %2" : "=v"(S1) : "v"(e1), "v"(o1)); \
    asm("v_pk_add_f16 %0, %1, %2" : "=v"(S2) : "v"(e2), "v"(o2)); \
    asm("v_pk_add_f16 %0, %1, %2" : "=v"(S3) : "v"(e3), "v"(o3)); }

// lgkm-only barrier: LDS ordered, global prefetch loads stay in flight
#define LBAR() { asm volatile("s_waitcnt lgkmcnt(0)" ::: "memory"); \
                 __builtin_amdgcn_s_barrier(); asm volatile("" ::: "memory"); }

__global__ __launch_bounds__(256)
void lga2_fused(const float* __restrict__ x, const float* __restrict__ f,
                float* __restrict__ out, int N, int C, int H, int W, int CPB) {
    const int tid = threadIdx.x;
    const int r = tid >> 4;            // temp-region row 0..15
    const int s = tid & 15;            // quad-strip 0..15
    const int oh0 = blockIdx.y * OH;
    const int ow0 = blockIdx.x * OW;
    const int CG = C / CPB;
    const int n  = blockIdx.z / CG;
    const int c0 = (blockIdx.z % CG) * CPB;
    const int HW = H * W;

    // [4] buffers: slices 0/1 are the active double-buffer; 2/3 exist only
    // to raise LDS to 29.2KB -> occupancy cap 5 blocks/CU -> RA VGPR budget
    // ~102 (kills the 64-clamp spill). Dummy-written so they are not elided.
    __shared__ unsigned sxU[4][20 * USH];   // x, channel-pair packed f16
    __shared__ unsigned stU[16 * USH];      // temp, channel-pair packed f16

    sxU[2][tid] = 0u;                       // keep slices 2/3 live (never read)
    sxU[3][tid] = 0u;

    // zero temp guard uints 0,1,66,67 per row
    if (tid < 64) {
        int row = tid >> 2, q = tid & 3;
        stU[row * USH + (q < 2 ? q : q + 64)] = 0u;
    }

    // ---- filter registers: 25 taps x 2 packed (col pairs), proven layout ----
    const int gh_f = oh0 - 2 + r;
    const int gwb  = ow0 - 2 + 4 * s;
    const bool rowok = (gh_f >= 0) && (gh_f < H);
    const bool p0ok = rowok && (gwb >= 0) && (gwb + 1 < W);
    const bool p1ok = rowok && (gwb + 3 < W);
    const float* fb = f + (size_t)(n * 25) * HW + (size_t)(rowok ? gh_f : 0) * W;

    unsigned frA[25], frB[25];
    #pragma unroll
    for (int t = 0; t < 25; ++t) {
        float2 v01 = p0ok ? *(const float2*)(fb + (size_t)t * HW + gwb)
                          : make_float2(0.f, 0.f);
        float2 v23 = p1ok ? *(const float2*)(fb + (size_t)t * HW + gwb + 2)
                          : make_float2(0.f, 0.f);
        frA[t] = pkh(v01.x, v01.y);
        frB[t] = pkh(v23.x, v23.y);
        if (t == 12) __builtin_amdgcn_sched_barrier(0);  // 2 load batches
    }
    #pragma unroll
    for (int t = 0; t < 25; ++t)
        asm volatile("" : "+v"(frA[t]), "+v"(frB[t]));   // pin packed filters

    // ---- staging: 340 quads (20 rows x 17 x 4 pixels), b128 per quad ----
    const int i1 = tid + 256;
    const bool has1 = (tid < 340 - 256);
    const int row0 = tid / 17, v0 = tid - row0 * 17;
    const int row1 = i1 / 17,  v1 = i1 - row1 * 17;
    const int g0h = oh0 - 4 + row0, g0c = ow0 - 4 + 4 * v0;
    const int g1h = oh0 - 4 + row1, g1c = ow0 - 4 + 4 * v1;
    const bool ok0 = (g0h >= 0) && (g0h < H) && (g0c >= 0) && (g0c + 3 < W);
    const bool ok1 = has1 && (g1h >= 0) && (g1h < H) && (g1c >= 0) && (g1c + 3 < W);
    const int off0 = ok0 ? (g0h * W + g0c) : 0;
    const int off1 = ok1 ? (g1h * W + g1c) : 0;
    const int l0u = row0 * USH + 4 * v0;   // b128-aligned
    const int l1u = row1 * USH + 4 * v1;

    const float4 z4 = make_float4(0.f, 0.f, 0.f, 0.f);
    const float* xc = x + (size_t)(n * C + c0) * HW;

#define PACK4(pa, pb) make_uint4(pkh(pa.x, pb.x), pkh(pa.y, pb.y), \
                                 pkh(pa.z, pb.z), pkh(pa.w, pb.w))

    {   // prologue: stage channel pair (0,1) -> buffer 0
        float4 pa = ok0 ? *(const float4*)(xc + off0) : z4;
        float4 pb = ok0 ? *(const float4*)(xc + HW + off0) : z4;
        *(uint4*)&sxU[0][l0u] = PACK4(pa, pb);
        if (has1) {
            float4 qa = ok1 ? *(const float4*)(xc + off1) : z4;
            float4 qb = ok1 ? *(const float4*)(xc + HW + off1) : z4;
            *(uint4*)&sxU[0][l1u] = PACK4(qa, qb);
        }
    }
    __syncthreads();

    const bool prow = (r >= 2) && (r <= 13) && (gh_f < H);
    const int rc = (r < 2) ? 2 : ((r > 13) ? 13 : r);
    float* op = out + ((size_t)(n * C + c0) * H + gh_f) * W + gwb;

    int cur = 0;
    for (int cp = 0; cp < CPB; cp += 2) {
        // issue prefetch for pair (cp+2, cp+3); landed at iteration end
        float4 n0a = z4, n0b = z4, n1a = z4, n1b = z4;
        const bool pf = (cp + 2 < CPB);
        if (pf) {
            const float* xn = xc + (size_t)(cp + 2) * HW;
            if (ok0) { n0a = *(const float4*)(xn + off0);
                       n0b = *(const float4*)(xn + HW + off0); }
            if (ok1) { n1a = *(const float4*)(xn + off1);
                       n1b = *(const float4*)(xn + HW + off1); }
        }

        // ---- pass 1: temp(r, cols 4s..4s+3) for both channels ----
        unsigned t0, t1, t2, t3;
        PASS2(sxU[cur], r, t0, t1, t2, t3)
        *(uint2*)&stU[r * USH + 2 + 4 * s] = make_uint2(t0, t1);
        *(uint2*)&stU[r * USH + 4 + 4 * s] = make_uint2(t2, t3);
        LBAR();   // temp visible

        // ---- pass 2 + stores ----
        PASS2(stU, rc - 2, t0, t1, t2, t3)
        if (prow) {
            union { unsigned u; h2v h; } U0, U1, U2, U3;
            U0.u = t0; U1.u = t1; U2.u = t2; U3.u = t3;
            float* oq = op + HW;   // channel cp+1
            if (s >= 1 && gwb + 1 < W) {
                *(float2*)op = make_float2((float)U0.h.x, (float)U1.h.x);
                *(float2*)oq = make_float2((float)U0.h.y, (float)U1.h.y);
            }
            if (s <= 14 && gwb + 3 < W) {
                *(float2*)(op + 2) = make_float2((float)U2.h.x, (float)U3.h.x);
                *(float2*)(oq + 2) = make_float2((float)U2.h.y, (float)U3.h.y);
            }
        }

        // ---- land prefetch into the other buffer ----
        if (pf) {
            unsigned* d = sxU[cur ^ 1];
            *(uint4*)&d[l0u] = PACK4(n0a, n0b);
            if (has1) *(uint4*)&d[l1u] = PACK4(n1a, n1b);
        }
        LBAR();   // next pair's x visible; temp reads drained
        cur ^= 1;
        op += 2 * (size_t)HW;
    }
}

extern "C" void kernel_launch(void* const* d_in, const int* in_sizes, int n_in,
                              void* d_out, int out_size, void* d_ws, size_t ws_size,
                              hipStream_t stream) {
    const float* x = (const float*)d_in[0];
    const float* f = (const float*)d_in[1];
    float* out = (float*)d_out;

    const int N = 2, C = 64, H = 256, W = 512;
    const int CPB = 32;                        // 2 channel groups
    const int CG = C / CPB;

    dim3 grid((W + OW - 1) / OW,               // 9
              (H + OH - 1) / OH,               // 22
              N * CG);                         // 4  -> 792 blocks of 256 thr
    lga2_fused<<<grid, 256, 0, stream>>>(x, f, out, N, C, H, W, CPB);
}